// Round 2
// baseline (650.534 us; speedup 1.0000x reference)
//
#include <hip/hip_runtime.h>
#include <hip/hip_bf16.h>
#include <math.h>

typedef __bf16 bf16_t;
typedef __attribute__((ext_vector_type(8))) __bf16 bf16x8;
typedef __attribute__((ext_vector_type(4))) __bf16 bf16x4;
typedef __attribute__((ext_vector_type(4))) float f32x4;

#define L_TOK 4680
#define DIM   1536
#define NH    12
#define HD    128
#define FRAME 1560
#define LPAD  4736
#define SCALE 0.08838834764831845f   // 1/sqrt(128)

__device__ __forceinline__ void gl_lds16(const bf16_t* g, bf16_t* l) {
  __builtin_amdgcn_global_load_lds(
      (const __attribute__((address_space(1))) unsigned int*)(g),
      (__attribute__((address_space(3))) unsigned int*)(l),
      16, 0, 0);
}

// ---------------- fp32 -> bf16 cast ----------------
__global__ __launch_bounds__(256) void cast_f32_bf16(const float* __restrict__ in,
                                                     bf16_t* __restrict__ out, int n4) {
  int i = blockIdx.x * 256 + threadIdx.x;
  if (i >= n4) return;
  float4 v = ((const float4*)in)[i];
  bf16x4 o;
  o[0] = (__bf16)v.x; o[1] = (__bf16)v.y; o[2] = (__bf16)v.z; o[3] = (__bf16)v.w;
  ((bf16x4*)out)[i] = o;
}

// ---------------- fused QKV GEMM: C = X * W^T + b ----------------
// 128x128 tile, BK=32, global_load_lds staging (m97 structure).
// seg 0 -> Q (row-major bf16), seg 1 -> K (row-major bf16),
// seg 2 -> V stored transposed: Vt[n][LPAD] (n = h*128+d), for attention staging.
__global__ __launch_bounds__(256) void gemm_qkv(
    const bf16_t* __restrict__ X,
    const bf16_t* __restrict__ Wq, const bf16_t* __restrict__ Wk, const bf16_t* __restrict__ Wv,
    const float* __restrict__ bq, const float* __restrict__ bk, const float* __restrict__ bv,
    bf16_t* __restrict__ Qo, bf16_t* __restrict__ Ko, bf16_t* __restrict__ Vt)
{
  __shared__ __align__(16) bf16_t Al[128 * 32];
  __shared__ __align__(16) bf16_t Bl[128 * 32];
  const int m0 = blockIdx.x * 128;
  const int nb = blockIdx.y;
  const int seg = nb / 12;
  const int n0 = (nb % 12) * 128;
  const bf16_t* W   = (seg == 0) ? Wq : (seg == 1) ? Wk : Wv;
  const float* bias = (seg == 0) ? bq : (seg == 1) ? bk : bv;

  const int tid = threadIdx.x;
  const int wave = tid >> 6, lane = tid & 63;
  const int quad = lane >> 4, l15 = lane & 15;
  const int wm = (wave >> 1) * 64, wn = (wave & 1) * 64;

  f32x4 acc[4][4];
#pragma unroll
  for (int i = 0; i < 4; ++i)
#pragma unroll
    for (int j = 0; j < 4; ++j) acc[i][j] = (f32x4){0.f, 0.f, 0.f, 0.f};

  // staging geometry: 8 chunks of 1KB each for A and B; wave w owns chunks 2w,2w+1
  const int c0 = wave * 2;
  const int fi0 = c0 * 512 + lane * 8;           // flat bf16 index in [128][32]
  const int r0 = fi0 >> 5, col0 = fi0 & 31;
  const int fi1 = fi0 + 512;
  const int r1 = fi1 >> 5, col1 = fi1 & 31;

  const bf16_t* agp0 = X + (size_t)(m0 + r0) * DIM + col0;
  const bf16_t* agp1 = X + (size_t)(m0 + r1) * DIM + col1;
  const bf16_t* bgp0 = W + (size_t)(n0 + r0) * DIM + col0;
  const bf16_t* bgp1 = W + (size_t)(n0 + r1) * DIM + col1;
  bf16_t* al0 = Al + c0 * 512 + lane * 8;
  bf16_t* al1 = al0 + 512;
  bf16_t* bl0 = Bl + c0 * 512 + lane * 8;
  bf16_t* bl1 = bl0 + 512;

  for (int k0 = 0; k0 < DIM; k0 += 32) {
    __syncthreads();
    gl_lds16(agp0 + k0, al0);
    gl_lds16(agp1 + k0, al1);
    gl_lds16(bgp0 + k0, bl0);
    gl_lds16(bgp1 + k0, bl1);
    __syncthreads();
    bf16x8 af[4], bfg[4];
#pragma unroll
    for (int i = 0; i < 4; ++i) {
      af[i]  = *(const bf16x8*)(Al + (wm + i * 16 + l15) * 32 + quad * 8);
      bfg[i] = *(const bf16x8*)(Bl + (wn + i * 16 + l15) * 32 + quad * 8);
    }
#pragma unroll
    for (int i = 0; i < 4; ++i)
#pragma unroll
      for (int j = 0; j < 4; ++j)
        acc[i][j] = __builtin_amdgcn_mfma_f32_16x16x32_bf16(af[i], bfg[j], acc[i][j], 0, 0, 0);
  }

  if (seg < 2) {
    bf16_t* Out = (seg == 0) ? Qo : Ko;
#pragma unroll
    for (int i = 0; i < 4; ++i) {
#pragma unroll
      for (int j = 0; j < 4; ++j) {
        const int n = n0 + wn + j * 16 + l15;
        const float bb = bias[n];
#pragma unroll
        for (int r = 0; r < 4; ++r) {
          const int m = m0 + wm + i * 16 + quad * 4 + r;
          if (m < L_TOK) Out[(size_t)m * DIM + n] = (bf16_t)(acc[i][j][r] + bb);
        }
      }
    }
  } else {
#pragma unroll
    for (int i = 0; i < 4; ++i) {
      const int mb = m0 + wm + i * 16 + quad * 4;
      if (mb < L_TOK) {   // L_TOK % 4 == 0, so whole 4-chunk valid
#pragma unroll
        for (int j = 0; j < 4; ++j) {
          const int n = n0 + wn + j * 16 + l15;
          const float bb = bias[n];
          bf16x4 p;
          p[0] = (__bf16)(acc[i][j][0] + bb);
          p[1] = (__bf16)(acc[i][j][1] + bb);
          p[2] = (__bf16)(acc[i][j][2] + bb);
          p[3] = (__bf16)(acc[i][j][3] + bb);
          *(bf16x4*)(Vt + (size_t)n * LPAD + mb) = p;
        }
      }
    }
  }
}

// ---------------- RMSNorm (over full dim) + RoPE, in place on Q and K ----------------
// Also folds the attention score scale (1/sqrt(128)) into Q.
__global__ __launch_bounds__(256) void rmsnorm_rope(
    bf16_t* __restrict__ Q, bf16_t* __restrict__ K,
    const float* __restrict__ gq, const float* __restrict__ gk,
    const float* __restrict__ freqs)
{
  const int l = blockIdx.x;
  const int tid = threadIdx.x;
  const int wave = tid >> 6, lane = tid & 63;
  bf16_t* qrow = Q + (size_t)l * DIM;
  bf16_t* krow = K + (size_t)l * DIM;

  unsigned int qb[3], kb[3];
  float sq = 0.f, sk = 0.f;
#pragma unroll
  for (int s = 0; s < 3; ++s) {
    const int p = s * 256 + tid;                // pair index 0..767
    qb[s] = *(const unsigned int*)(qrow + 2 * p);
    kb[s] = *(const unsigned int*)(krow + 2 * p);
    const __bf16* qh = (const __bf16*)&qb[s];
    const __bf16* kh = (const __bf16*)&kb[s];
    const float q0 = (float)qh[0], q1 = (float)qh[1];
    const float k0 = (float)kh[0], k1 = (float)kh[1];
    sq += q0 * q0 + q1 * q1;
    sk += k0 * k0 + k1 * k1;
  }
#pragma unroll
  for (int off = 1; off < 64; off <<= 1) {
    sq += __shfl_xor(sq, off);
    sk += __shfl_xor(sk, off);
  }
  __shared__ float rq_s[4], rk_s[4];
  if (lane == 0) { rq_s[wave] = sq; rk_s[wave] = sk; }
  __syncthreads();
  sq = rq_s[0] + rq_s[1] + rq_s[2] + rq_s[3];
  sk = rk_s[0] + rk_s[1] + rk_s[2] + rk_s[3];
  const float rnq = rsqrtf(sq * (1.f / DIM) + 1e-6f);
  const float rnk = rsqrtf(sk * (1.f / DIM) + 1e-6f);

  const int t = l / FRAME;
  const int rem = l - t * FRAME;
  const int hh = rem / 52;
  const int ww = rem - hh * 52;

#pragma unroll
  for (int s = 0; s < 3; ++s) {
    const int p = s * 256 + tid;
    const int j = p & 63;                        // pair index within head (c=64)
    const int sel = (j < 22) ? t : (j < 43) ? hh : ww;
    const float ang = freqs[sel * 64 + j];
    float sn, cs;
    __sincosf(ang, &sn, &cs);
    const __bf16* qh = (const __bf16*)&qb[s];
    const __bf16* kh = (const __bf16*)&kb[s];
    // Q (with score scale folded in)
    {
      const float g0 = gq[2 * p], g1 = gq[2 * p + 1];
      const float re = (float)qh[0] * rnq * g0;
      const float im = (float)qh[1] * rnq * g1;
      unsigned int o;
      __bf16* oh = (__bf16*)&o;
      oh[0] = (__bf16)((re * cs - im * sn) * SCALE);
      oh[1] = (__bf16)((re * sn + im * cs) * SCALE);
      *(unsigned int*)(qrow + 2 * p) = o;
    }
    // K
    {
      const float g0 = gk[2 * p], g1 = gk[2 * p + 1];
      const float re = (float)kh[0] * rnk * g0;
      const float im = (float)kh[1] * rnk * g1;
      unsigned int o;
      __bf16* oh = (__bf16*)&o;
      oh[0] = (__bf16)(re * cs - im * sn);
      oh[1] = (__bf16)(re * sn + im * cs);
      *(unsigned int*)(krow + 2 * p) = o;
    }
  }
}

// ---------------- flash attention, frame-causal mask ----------------
// block = (64-query tile, head); 4 waves x 16 q-rows; 16x16x32 MFMA.
__global__ __launch_bounds__(256) void attn(
    const bf16_t* __restrict__ Q, const bf16_t* __restrict__ K,
    const bf16_t* __restrict__ Vt, bf16_t* __restrict__ O)
{
  __shared__ __align__(16) bf16_t Kl[64][136];
  __shared__ __align__(16) bf16_t Vl[128][72];
  __shared__ __align__(16) float  Sl[4][16][68];

  const int qb = (int)gridDim.x - 1 - (int)blockIdx.x;  // heavy tiles first
  const int h = blockIdx.y;
  const int tid = threadIdx.x;
  const int wave = tid >> 6, lane = tid & 63;
  const int quad = lane >> 4, l15 = lane & 15;
  const int q0 = qb * 64;

  bf16x8 qf[4];
  {
    const int qrow = q0 + wave * 16 + l15;
    const bf16_t* qp = Q + (size_t)qrow * DIM + h * HD + quad * 8;
#pragma unroll
    for (int s = 0; s < 4; ++s) qf[s] = *(const bf16x8*)(qp + s * 32);
  }
  const int rr = lane >> 2, part = lane & 3;
  const int myl = q0 + wave * 16 + rr;
  const int lcl = (myl < L_TOK - 1) ? myl : (L_TOK - 1);
  const int kend = FRAME * (lcl / FRAME + 1);
  float m_run = -__builtin_inff(), l_run = 0.f;
  f32x4 oacc[8];
#pragma unroll
  for (int i = 0; i < 8; ++i) oacc[i] = (f32x4){0.f, 0.f, 0.f, 0.f};

  const int lastl = (q0 + 63 < L_TOK - 1) ? (q0 + 63) : (L_TOK - 1);
  const int nkt = (FRAME * (lastl / FRAME + 1) + 63) >> 6;

  for (int kt = 0; kt < nkt; ++kt) {
    const int kb = kt * 64;
    __syncthreads();
    // stage K tile (64 keys x 128 d), padded rows
#pragma unroll
    for (int it = 0; it < 4; ++it) {
      const int c = tid + it * 256;
      const int r = c >> 4, cc = (c & 15) << 3;
      *(uint4*)(&Kl[r][cc]) = *(const uint4*)(K + (size_t)(kb + r) * DIM + h * HD + cc);
    }
    // stage V tile transposed from Vt[dim][LPAD]
#pragma unroll
    for (int it = 0; it < 4; ++it) {
      const int c = tid + it * 256;
      const int d = c >> 3, cc = (c & 7) << 3;
      *(uint4*)(&Vl[d][cc]) = *(const uint4*)(Vt + (size_t)(h * HD + d) * LPAD + kb + cc);
    }
    __syncthreads();

    // S strip: this wave's 16 q-rows x 64 keys (scale already folded into Q)
    f32x4 s[4];
#pragma unroll
    for (int nt = 0; nt < 4; ++nt) s[nt] = (f32x4){0.f, 0.f, 0.f, 0.f};
#pragma unroll
    for (int ds = 0; ds < 4; ++ds) {
#pragma unroll
      for (int nt = 0; nt < 4; ++nt) {
        bf16x8 kf = *(const bf16x8*)(&Kl[nt * 16 + l15][ds * 32 + quad * 8]);
        s[nt] = __builtin_amdgcn_mfma_f32_16x16x32_bf16(qf[ds], kf, s[nt], 0, 0, 0);
      }
    }
#pragma unroll
    for (int nt = 0; nt < 4; ++nt)
#pragma unroll
      for (int r = 0; r < 4; ++r)
        Sl[wave][quad * 4 + r][nt * 16 + l15] = s[nt][r];
    __builtin_amdgcn_wave_barrier();

    // online softmax: 4 lanes per row
    float vals[16];
    float mx = -__builtin_inff();
#pragma unroll
    for (int c4 = 0; c4 < 4; ++c4) {
      float4 v = *(const float4*)(&Sl[wave][rr][part * 16 + c4 * 4]);
      const float* vv = (const float*)&v;
#pragma unroll
      for (int jj = 0; jj < 4; ++jj) {
        const int col = kb + part * 16 + c4 * 4 + jj;
        const float sv = (col < kend) ? vv[jj] : -__builtin_inff();
        vals[c4 * 4 + jj] = sv;
        mx = fmaxf(mx, sv);
      }
    }
    mx = fmaxf(mx, __shfl_xor(mx, 1));
    mx = fmaxf(mx, __shfl_xor(mx, 2));
    const float m_new = fmaxf(m_run, mx);
    float ssum = 0.f;
#pragma unroll
    for (int c4 = 0; c4 < 4; ++c4) {
      float4 pv;
      float* pp = (float*)&pv;
#pragma unroll
      for (int jj = 0; jj < 4; ++jj) {
        const float p = __expf(vals[c4 * 4 + jj] - m_new);
        pp[jj] = p;
        ssum += p;
      }
      *(float4*)(&Sl[wave][rr][part * 16 + c4 * 4]) = pv;
    }
    __builtin_amdgcn_wave_barrier();
    ssum += __shfl_xor(ssum, 1);
    ssum += __shfl_xor(ssum, 2);
    const float alpha = __expf(m_run - m_new);   // 0 on first tile (m_run=-inf)
    l_run = l_run * alpha + ssum;
    m_run = m_new;

    const float a0 = __shfl(alpha, (quad * 4 + 0) * 4);
    const float a1 = __shfl(alpha, (quad * 4 + 1) * 4);
    const float a2 = __shfl(alpha, (quad * 4 + 2) * 4);
    const float a3 = __shfl(alpha, (quad * 4 + 3) * 4);
#pragma unroll
    for (int nt = 0; nt < 8; ++nt) {
      oacc[nt][0] *= a0; oacc[nt][1] *= a1; oacc[nt][2] *= a2; oacc[nt][3] *= a3;
    }

    // P frags (A-layout) from LDS fp32 -> bf16
    bf16x8 pf[2];
#pragma unroll
    for (int kk = 0; kk < 2; ++kk) {
      float4 f0 = *(const float4*)(&Sl[wave][l15][kk * 32 + quad * 8]);
      float4 f1 = *(const float4*)(&Sl[wave][l15][kk * 32 + quad * 8 + 4]);
      bf16x8 t;
      t[0] = (__bf16)f0.x; t[1] = (__bf16)f0.y; t[2] = (__bf16)f0.z; t[3] = (__bf16)f0.w;
      t[4] = (__bf16)f1.x; t[5] = (__bf16)f1.y; t[6] = (__bf16)f1.z; t[7] = (__bf16)f1.w;
      pf[kk] = t;
    }
#pragma unroll
    for (int nt = 0; nt < 8; ++nt) {
#pragma unroll
      for (int kk = 0; kk < 2; ++kk) {
        bf16x8 vf = *(const bf16x8*)(&Vl[nt * 16 + l15][kk * 32 + quad * 8]);
        oacc[nt] = __builtin_amdgcn_mfma_f32_16x16x32_bf16(pf[kk], vf, oacc[nt], 0, 0, 0);
      }
    }
  }

  const float li = 1.f / l_run;
  const float li0 = __shfl(li, (quad * 4 + 0) * 4);
  const float li1 = __shfl(li, (quad * 4 + 1) * 4);
  const float li2 = __shfl(li, (quad * 4 + 2) * 4);
  const float li3 = __shfl(li, (quad * 4 + 3) * 4);
  const int mrow = q0 + wave * 16 + quad * 4;
  if (mrow < L_TOK) {   // L_TOK % 4 == 0
#pragma unroll
    for (int nt = 0; nt < 8; ++nt) {
      const int n = h * HD + nt * 16 + l15;
      O[(size_t)(mrow + 0) * DIM + n] = (bf16_t)(oacc[nt][0] * li0);
      O[(size_t)(mrow + 1) * DIM + n] = (bf16_t)(oacc[nt][1] * li1);
      O[(size_t)(mrow + 2) * DIM + n] = (bf16_t)(oacc[nt][2] * li2);
      O[(size_t)(mrow + 3) * DIM + n] = (bf16_t)(oacc[nt][3] * li3);
    }
  }
}

// ---------------- output projection: out = A * Wo^T + bo (fp32 out) ----------------
__global__ __launch_bounds__(256) void gemm_proj(
    const bf16_t* __restrict__ A, const bf16_t* __restrict__ W,
    const float* __restrict__ bias, float* __restrict__ out)
{
  __shared__ __align__(16) bf16_t Al[128 * 32];
  __shared__ __align__(16) bf16_t Bl[128 * 32];
  const int m0 = blockIdx.x * 128;
  const int n0 = blockIdx.y * 128;

  const int tid = threadIdx.x;
  const int wave = tid >> 6, lane = tid & 63;
  const int quad = lane >> 4, l15 = lane & 15;
  const int wm = (wave >> 1) * 64, wn = (wave & 1) * 64;

  f32x4 acc[4][4];
#pragma unroll
  for (int i = 0; i < 4; ++i)
#pragma unroll
    for (int j = 0; j < 4; ++j) acc[i][j] = (f32x4){0.f, 0.f, 0.f, 0.f};

  const int c0 = wave * 2;
  const int fi0 = c0 * 512 + lane * 8;
  const int r0 = fi0 >> 5, col0 = fi0 & 31;
  const int fi1 = fi0 + 512;
  const int r1 = fi1 >> 5, col1 = fi1 & 31;

  const bf16_t* agp0 = A + (size_t)(m0 + r0) * DIM + col0;
  const bf16_t* agp1 = A + (size_t)(m0 + r1) * DIM + col1;
  const bf16_t* bgp0 = W + (size_t)(n0 + r0) * DIM + col0;
  const bf16_t* bgp1 = W + (size_t)(n0 + r1) * DIM + col1;
  bf16_t* al0 = Al + c0 * 512 + lane * 8;
  bf16_t* al1 = al0 + 512;
  bf16_t* bl0 = Bl + c0 * 512 + lane * 8;
  bf16_t* bl1 = bl0 + 512;

  for (int k0 = 0; k0 < DIM; k0 += 32) {
    __syncthreads();
    gl_lds16(agp0 + k0, al0);
    gl_lds16(agp1 + k0, al1);
    gl_lds16(bgp0 + k0, bl0);
    gl_lds16(bgp1 + k0, bl1);
    __syncthreads();
    bf16x8 af[4], bfg[4];
#pragma unroll
    for (int i = 0; i < 4; ++i) {
      af[i]  = *(const bf16x8*)(Al + (wm + i * 16 + l15) * 32 + quad * 8);
      bfg[i] = *(const bf16x8*)(Bl + (wn + i * 16 + l15) * 32 + quad * 8);
    }
#pragma unroll
    for (int i = 0; i < 4; ++i)
#pragma unroll
      for (int j = 0; j < 4; ++j)
        acc[i][j] = __builtin_amdgcn_mfma_f32_16x16x32_bf16(af[i], bfg[j], acc[i][j], 0, 0, 0);
  }

#pragma unroll
  for (int i = 0; i < 4; ++i) {
#pragma unroll
    for (int j = 0; j < 4; ++j) {
      const int n = n0 + wn + j * 16 + l15;
      const float bb = bias[n];
#pragma unroll
      for (int r = 0; r < 4; ++r) {
        const int m = m0 + wm + i * 16 + quad * 4 + r;
        if (m < L_TOK) out[(size_t)m * DIM + n] = acc[i][j][r] + bb;
      }
    }
  }
}

extern "C" void kernel_launch(void* const* d_in, const int* in_sizes, int n_in,
                              void* d_out, int out_size, void* d_ws, size_t ws_size,
                              hipStream_t stream) {
  (void)in_sizes; (void)n_in; (void)out_size;
  const float* x  = (const float*)d_in[0];
  const float* fr = (const float*)d_in[1];
  const float* Wq = (const float*)d_in[2];
  const float* bq = (const float*)d_in[3];
  const float* Wk = (const float*)d_in[4];
  const float* bk = (const float*)d_in[5];
  const float* Wv = (const float*)d_in[6];
  const float* bv = (const float*)d_in[7];
  const float* Wo = (const float*)d_in[8];
  const float* bo = (const float*)d_in[9];
  const float* gq = (const float*)d_in[10];
  const float* gk = (const float*)d_in[11];
  float* out = (float*)d_out;

  char* ws = (char*)d_ws;
  size_t off = 0;
  auto alloc = [&](size_t bytes) {
    char* p = ws + off;
    off += (bytes + 255) & ~(size_t)255;
    return p;
  };
  const size_t lbuf = (size_t)LPAD * DIM * 2;
  const size_t wbuf = (size_t)DIM * DIM * 2;
  bf16_t* xb  = (bf16_t*)alloc(lbuf);
  bf16_t* Wqb = (bf16_t*)alloc(wbuf);
  bf16_t* Wkb = (bf16_t*)alloc(wbuf);
  bf16_t* Wvb = (bf16_t*)alloc(wbuf);
  bf16_t* Wob = (bf16_t*)alloc(wbuf);
  bf16_t* Qb  = (bf16_t*)alloc(lbuf);
  bf16_t* Kb  = (bf16_t*)alloc(lbuf);
  bf16_t* Vtb = (bf16_t*)alloc(lbuf);
  bf16_t* Ob  = (bf16_t*)alloc(lbuf);
  if (off > ws_size) return;  // workspace too small: fail loudly via wrong output

  const int n4x = L_TOK * DIM / 4;
  const int n4w = DIM * DIM / 4;
  cast_f32_bf16<<<(n4x + 255) / 256, 256, 0, stream>>>(x, xb, n4x);
  cast_f32_bf16<<<(n4w + 255) / 256, 256, 0, stream>>>(Wq, Wqb, n4w);
  cast_f32_bf16<<<(n4w + 255) / 256, 256, 0, stream>>>(Wk, Wkb, n4w);
  cast_f32_bf16<<<(n4w + 255) / 256, 256, 0, stream>>>(Wv, Wvb, n4w);
  cast_f32_bf16<<<(n4w + 255) / 256, 256, 0, stream>>>(Wo, Wob, n4w);

  gemm_qkv<<<dim3(LPAD / 128, 36), 256, 0, stream>>>(xb, Wqb, Wkb, Wvb, bq, bk, bv,
                                                     Qb, Kb, Vtb);
  rmsnorm_rope<<<L_TOK, 256, 0, stream>>>(Qb, Kb, gq, gk, fr);
  attn<<<dim3(LPAD / 64, NH), 256, 0, stream>>>(Qb, Kb, Vtb, Ob);
  gemm_proj<<<dim3(LPAD / 128, 12), 256, 0, stream>>>(Ob, Wob, bo, out);
}